// Round 3
// baseline (421.133 us; speedup 1.0000x reference)
//
#include <hip/hip_runtime.h>

typedef unsigned short u16;
using bf16x8 = __attribute__((ext_vector_type(8))) __bf16;
using f32x4  = __attribute__((ext_vector_type(4))) float;

#define GL_TO_LDS(gp, sp) \
  __builtin_amdgcn_global_load_lds((const __attribute__((address_space(1))) void*)(gp), \
                                   (__attribute__((address_space(3))) void*)(sp), 16, 0, 0)

__device__ __forceinline__ u16 f2bf(float f){
  unsigned u = __builtin_bit_cast(unsigned, f);
  u += 0x7fffu + ((u >> 16) & 1u);
  return (u16)(u >> 16);
}
__device__ __forceinline__ float bf2f(u16 v){
  unsigned u = ((unsigned)v) << 16;
  return __builtin_bit_cast(float, u);
}

constexpr int SB = 4, SL = 4096, SD = 1024;
constexpr int GM = SB * SL, GN = SD, GK = SD;      // 16384 x 1024 x 1024
constexpr int NT = GK / 64;                        // 16 K-tiles of BK=64
constexpr int NCHUNK = 64, CH = SL / NCHUNK;       // 64 chunks of 64
constexpr float EPS_PHAZOR = 1e-5f;
constexpr float LOG2_SCALE = -9.965784284662087f;  // log2(0.001)

// ---------------- f32 -> bf16 conversion of x and the 4 weight matrices ----------------
__global__ __launch_bounds__(256) void k_convert(
    const float4* __restrict__ x4, const float4* __restrict__ wz4,
    const float4* __restrict__ wza4, const float4* __restrict__ wy4,
    const float4* __restrict__ wya4, u16* __restrict__ xb, u16* __restrict__ wb){
  int gid = blockIdx.x * 256 + threadIdx.x;   // each handles 8 floats
  const float4* src; u16* dst;
  if (gid < (GM * GK / 8)){
    src = x4 + (size_t)gid * 2; dst = xb + (size_t)gid * 8;
  } else {
    int g2 = gid - GM * GK / 8;
    int which = g2 >> 17, off = g2 & 0x1ffff;
    const float4* s4 = which == 0 ? wz4 : which == 1 ? wza4 : which == 2 ? wy4 : wya4;
    src = s4 + (size_t)off * 2; dst = wb + (size_t)which * (GK * GN) + (size_t)off * 8;
  }
  float4 a = src[0], b = src[1];
  u16 r[8] = {f2bf(a.x), f2bf(a.y), f2bf(a.z), f2bf(a.w),
              f2bf(b.x), f2bf(b.y), f2bf(b.z), f2bf(b.w)};
  *reinterpret_cast<uint4*>(dst) = *reinterpret_cast<const uint4*>(r);
}

// ---------------- 256x256 8-phase single GEMM with fused gate epilogue ----------------
// MODE 0: out(bf16) = f2bf(silu(acc + bias))          [gate producer]
// MODE 1: out(f32)  = (acc + bias) * bf2f(gate[..])   [final y]
// MODE 2: out(bf16) = f2bf((acc + bias) * bf2f(gate)) [z, bf16]
// A [M][K] bf16, W [N][K] bf16 (out = A @ W^T). Tile 256x256, BK=64, 8 waves (2M x 4N),
// wave owns 128x64. LDS 128KB: {A,B} x dbuf x [256 rows][8 slots of 8 elems, XOR-swizzled].
#define LDA(dst, q, pk) { _Pragma("unroll") for (int mf = 0; mf < 4; ++mf) \
  dst[mf] = *reinterpret_cast<const bf16x8*>(&lds[abase + ((q)*64 + mf*16)*64 + (pk)*8]); }
#define LDB(dst, pk) { _Pragma("unroll") for (int nf = 0; nf < 4; ++nf) \
  dst[nf] = *reinterpret_cast<const bf16x8*>(&lds[bbase + (nf*16)*64 + (pk)*8]); }
#define MM(qq, af, bfr) { _Pragma("unroll") for (int mf = 0; mf < 4; ++mf) \
  _Pragma("unroll") for (int nf = 0; nf < 4; ++nf) \
    acc[(qq)*4+mf][nf] = __builtin_amdgcn_mfma_f32_16x16x32_bf16(af[mf], bfr[nf], acc[(qq)*4+mf][nf], 0, 0, 0); }

template<int MODE>
__global__ __launch_bounds__(512, 2) void k_gemm8(
    const u16* __restrict__ A, const u16* __restrict__ W,
    const float* __restrict__ bias, const u16* __restrict__ gate,
    void* __restrict__ outp){
  __shared__ u16 lds[65536];   // 128 KiB

  const int tid = threadIdx.x;
  const int w = tid >> 6, ln = tid & 63;
  const int wm = w >> 2, wn = w & 3;          // wave grid 2M x 4N
  const int lr = ln & 15, lg = ln >> 4;
  const int bm = blockIdx.y, bn = blockIdx.x;

  // ---- staging: 8 x 16B loads/thread/K-tile; phys slot (tid&7) at row r holds
  // logical k-chunk (tid&7)^(r&7); read side inverts with row%8 == lr%8 ----
  const int r0 = tid >> 3;                    // row within each 64-row group
  const int l8 = ((tid & 7) ^ (r0 & 7)) * 8;  // logical k element offset for this phys slot
  const u16* Arow = A + (size_t)(bm * 256) * GK + l8;
  const u16* Wrow = W + (size_t)(bn * 256) * GK + l8;
  const u16* srcs[8];
  srcs[0] = Arow + (size_t)(r0      ) * GK;
  srcs[1] = Arow + (size_t)(r0 +  64) * GK;
  srcs[2] = Arow + (size_t)(r0 + 128) * GK;
  srcs[3] = Arow + (size_t)(r0 + 192) * GK;
  srcs[4] = Wrow + (size_t)(r0      ) * GK;
  srcs[5] = Wrow + (size_t)(r0 +  64) * GK;
  srcs[6] = Wrow + (size_t)(r0 + 128) * GK;
  srcs[7] = Wrow + (size_t)(r0 + 192) * GK;
  int dstb[8];
  dstb[0] = 0     + w * 512;  dstb[1] = 4096  + w * 512;
  dstb[2] = 8192  + w * 512;  dstb[3] = 12288 + w * 512;
  dstb[4] = 32768 + w * 512;  dstb[5] = 36864 + w * 512;
  dstb[6] = 40960 + w * 512;  dstb[7] = 45056 + w * 512;

  const int pk0 = lg ^ (lr & 7);        // phys slot for k-step 0 (logical chunk lg)
  const int pk1 = (4 + lg) ^ (lr & 7);  // phys slot for k-step 1 (logical chunk 4+lg)

  f32x4 acc[8][4] = {};

  // prologue: stage tile 0 into slot 0
  {
    #pragma unroll
    for (int u = 0; u < 8; ++u) GL_TO_LDS(srcs[u], &lds[dstb[u]]);
    asm volatile("s_waitcnt vmcnt(0)" ::: "memory");
    __builtin_amdgcn_s_barrier();
  }

  for (int t = 0; t < NT; ++t){
    const int sl = t & 1;
    const int abase = sl * 16384 + wm * 8192 + lr * 64;
    const int bbase = 32768 + sl * 16384 + (wn >> 1) * 8192 + ((wn & 1) * 64 + lr) * 64;
    bf16x8 a0[4], a1[4], b0[4], b1[4];

    // P1: read (q0,k0)+(B k0); issue ALL of tile t+1's stages (3 phases of slack)
    LDA(a0, 0, pk0); LDB(b0, pk0);
    if (t + 1 < NT){
      const int sb = (sl ^ 1) * 16384;
      #pragma unroll
      for (int u = 0; u < 8; ++u) GL_TO_LDS(srcs[u] + (t + 1) * 64, &lds[dstb[u] + sb]);
    }
    __builtin_amdgcn_s_setprio(1); MM(0, a0, b0); __builtin_amdgcn_s_setprio(0);
    __builtin_amdgcn_s_barrier();
    // P2: (q1,k0), B regs reused
    LDA(a1, 1, pk0);
    __builtin_amdgcn_s_setprio(1); MM(1, a1, b0); __builtin_amdgcn_s_setprio(0);
    __builtin_amdgcn_s_barrier();
    // P3: (q0,k1)+(B k1)
    LDA(a0, 0, pk1); LDB(b1, pk1);
    __builtin_amdgcn_s_setprio(1); MM(0, a0, b1); __builtin_amdgcn_s_setprio(0);
    __builtin_amdgcn_s_barrier();
    // P4: (q1,k1); counted wait for t+1's stages just before slot flip
    LDA(a1, 1, pk1);
    __builtin_amdgcn_s_setprio(1); MM(1, a1, b1); __builtin_amdgcn_s_setprio(0);
    if (t + 1 < NT) asm volatile("s_waitcnt vmcnt(0)" ::: "memory");
    __builtin_amdgcn_s_barrier();
  }

  // ---- epilogue: C/D layout col=lane&15, row=(lane>>4)*4+reg [m89] ----
  #pragma unroll
  for (int nf = 0; nf < 4; ++nf){
    const int col = bn * 256 + wn * 64 + nf * 16 + lr;
    const float bb = bias[col];
    #pragma unroll
    for (int ri = 0; ri < 8; ++ri){
      const int rowb = bm * 256 + wm * 128 + ri * 16 + lg * 4;
      f32x4 v = acc[ri][nf];
      if constexpr(MODE == 0){
        u16* gout = (u16*)outp;
        #pragma unroll
        for (int r = 0; r < 4; ++r){
          float p = v[r] + bb;
          float s = p / (1.f + __expf(-p));
          gout[(size_t)(rowb + r) * GN + col] = f2bf(s);
        }
      } else if constexpr(MODE == 1){
        float* fout = (float*)outp;
        #pragma unroll
        for (int r = 0; r < 4; ++r){
          float g = bf2f(gate[(size_t)(rowb + r) * GN + col]);
          fout[(size_t)(rowb + r) * GN + col] = (v[r] + bb) * g;
        }
      } else {
        u16* zout = (u16*)outp;
        #pragma unroll
        for (int r = 0; r < 4; ++r){
          float g = bf2f(gate[(size_t)(rowb + r) * GN + col]);
          zout[(size_t)(rowb + r) * GN + col] = f2bf((v[r] + bb) * g);
        }
      }
    }
  }
}

// ---------------- chunked complex scan: h[l] = r*h[l-1] + z[l], h[-1] = last_conv ----------------
__global__ __launch_bounds__(256) void k_scan1(const u16* __restrict__ z, float2* __restrict__ carry){
  const int d = blockIdx.x * 256 + threadIdx.x;
  const int c = blockIdx.y, b = blockIdx.z;
  const float sc = exp2f(LOG2_SCALE * ((float)d * (1.0f / 1023.0f)));
  float si, co; sincosf(sc, &si, &co);
  const float er = expf(EPS_PHAZOR);
  const float rre = er * co, rim = er * si;
  const u16* zp = z + ((size_t)b * SL + (size_t)c * CH) * SD + d;
  float hre = 0.f, him = 0.f;
  #pragma unroll 8
  for (int i = 0; i < CH; i++){
    float zv = bf2f(zp[i * SD]);
    float nr = fmaf(rre, hre, fmaf(-rim, him, zv));
    him = fmaf(rre, him, rim * hre);
    hre = nr;
  }
  carry[(size_t)(b * NCHUNK + c) * SD + d] = make_float2(hre, him);
}

__global__ __launch_bounds__(256) void k_scan2(const float2* __restrict__ carry,
    const float* __restrict__ lcre, const float* __restrict__ lcim, float2* __restrict__ hin){
  const int idx = blockIdx.x * 256 + threadIdx.x;  // b*1024 + d
  const int b = idx >> 10, d = idx & 1023;
  const float sc = exp2f(LOG2_SCALE * ((float)d * (1.0f / 1023.0f)));
  float si, co; sincosf((float)CH * sc, &si, &co);
  const float eC = expf((float)CH * EPS_PHAZOR);
  const float Rre = eC * co, Rim = eC * si;
  float hre = lcre[d], him = lcim[d];
  for (int c = 0; c < NCHUNK; c++){
    const size_t o = (size_t)(b * NCHUNK + c) * SD + d;
    hin[o] = make_float2(hre, him);
    float2 cv = carry[o];
    float nr = fmaf(Rre, hre, fmaf(-Rim, him, cv.x));
    him = fmaf(Rre, him, fmaf(Rim, hre, cv.y));
    hre = nr;
  }
}

__global__ __launch_bounds__(256) void k_scan3(u16* __restrict__ zh, const float2* __restrict__ hin){
  const int d = blockIdx.x * 256 + threadIdx.x;
  const int c = blockIdx.y, b = blockIdx.z;
  const float sc = exp2f(LOG2_SCALE * ((float)d * (1.0f / 1023.0f)));
  float si, co; sincosf(sc, &si, &co);
  const float er = expf(EPS_PHAZOR);
  const float rre = er * co, rim = er * si;
  float2 h0 = hin[(size_t)(b * NCHUNK + c) * SD + d];
  float hre = h0.x, him = h0.y;
  u16* zp = zh + ((size_t)b * SL + (size_t)c * CH) * SD + d;
  #pragma unroll 8
  for (int i = 0; i < CH; i++){
    float zv = bf2f(zp[i * SD]);
    float nr = fmaf(rre, hre, fmaf(-rim, him, zv));
    him = fmaf(rre, him, rim * hre);
    hre = nr;
    zp[i * SD] = f2bf(hre);   // in-place: z -> Re(h) (bf16)
  }
}

// ---------------- RMSNorm row kernel (bf16 h -> bf16 normed) ----------------
__global__ __launch_bounds__(256) void k_rmsnorm(const u16* __restrict__ h,
    const float* __restrict__ nw, u16* __restrict__ outb){
  const int row = blockIdx.x, tid = threadIdx.x;
  const ushort4 hv = reinterpret_cast<const ushort4*>(h + (size_t)row * SD)[tid];
  float v0 = bf2f(hv.x), v1 = bf2f(hv.y), v2 = bf2f(hv.z), v3 = bf2f(hv.w);
  float ss = v0 * v0 + v1 * v1 + v2 * v2 + v3 * v3;
  #pragma unroll
  for (int o = 32; o; o >>= 1) ss += __shfl_down(ss, o, 64);
  __shared__ float red[5];
  const int lane = tid & 63, wid = tid >> 6;
  if (lane == 0) red[wid] = ss;
  __syncthreads();
  if (tid == 0) red[4] = rsqrtf((red[0] + red[1] + red[2] + red[3]) * (1.0f / (float)SD) + 1e-6f);
  __syncthreads();
  const float inv = red[4];
  const float4 w = reinterpret_cast<const float4*>(nw)[tid];
  u16 r[4] = { f2bf(v0 * inv * w.x), f2bf(v1 * inv * w.y),
               f2bf(v2 * inv * w.z), f2bf(v3 * inv * w.w) };
  reinterpret_cast<ushort4*>(outb + (size_t)row * SD)[tid] = *reinterpret_cast<const ushort4*>(r);
}

// ---------------- launch ----------------
extern "C" void kernel_launch(void* const* d_in, const int* in_sizes, int n_in,
                              void* d_out, int out_size, void* d_ws, size_t ws_size,
                              hipStream_t stream){
  const float* x    = (const float*)d_in[0];
  const float* Wz   = (const float*)d_in[1];
  const float* bz   = (const float*)d_in[2];
  const float* Wza  = (const float*)d_in[3];
  const float* bza  = (const float*)d_in[4];
  const float* Wy   = (const float*)d_in[5];
  const float* by   = (const float*)d_in[6];
  const float* Wya  = (const float*)d_in[7];
  const float* bya  = (const float*)d_in[8];
  const float* nw   = (const float*)d_in[9];
  const float* lcre = (const float*)d_in[10];
  const float* lcim = (const float*)d_in[11];

  char* ws = (char*)d_ws;
  // workspace (136 MiB total — same footprint round 1 proved available):
  //  [0,32M)    xb (bf16 x); dead after the 3 input GEMMs -> normedb reuses it
  //  [32M,40M)  wb: Wz,Wza,Wy,Wya bf16 (2 MiB each)
  //  [40M,72M)  gz (bf16 gate for z, 32 MiB); dead after gemm_z -> carry/hin overlay
  //  [72M,104M) gy (bf16 gate for y, 32 MiB); live until final gemm
  //  [104M,136M) zb (bf16 z -> Re(h) in place, 32 MiB)
  u16*    xb      = (u16*)(ws);
  u16*    normedb = (u16*)(ws);
  u16*    wb      = (u16*)(ws + (32ull << 20));
  u16*    gz      = (u16*)(ws + (40ull << 20));
  float2* carry   = (float2*)(ws + (40ull << 20));
  float2* hin     = (float2*)(ws + (42ull << 20));
  u16*    gy      = (u16*)(ws + (72ull << 20));
  u16*    zb      = (u16*)(ws + (104ull << 20));
  float*  y       = (float*)d_out;

  const size_t WSZ = (size_t)GK * GN;  // 1M elements per weight
  dim3 ggrid(GN / 256, GM / 256);      // 4 x 64 = 256 blocks = 1/CU

  k_convert<<<10240, 256, 0, stream>>>((const float4*)x, (const float4*)Wz, (const float4*)Wza,
                                       (const float4*)Wy, (const float4*)Wya, xb, wb);
  // gy = silu(x@Wya^T + bya)
  k_gemm8<0><<<ggrid, 512, 0, stream>>>(xb, wb + 3 * WSZ, bya, nullptr, gy);
  // gz = silu(x@Wza^T + bza)
  k_gemm8<0><<<ggrid, 512, 0, stream>>>(xb, wb + 1 * WSZ, bza, nullptr, gz);
  // z = (x@Wz^T + bz) * gz   (bf16)
  k_gemm8<2><<<ggrid, 512, 0, stream>>>(xb, wb + 0 * WSZ, bz, gz, zb);
  k_scan1<<<dim3(SD / 256, NCHUNK, SB), 256, 0, stream>>>(zb, carry);
  k_scan2<<<(SB * SD) / 256, 256, 0, stream>>>(carry, lcre, lcim, hin);
  k_scan3<<<dim3(SD / 256, NCHUNK, SB), 256, 0, stream>>>(zb, hin);
  k_rmsnorm<<<GM, 256, 0, stream>>>(zb, nw, normedb);
  // y = (normed@Wy^T + by) * gy
  k_gemm8<1><<<ggrid, 512, 0, stream>>>(normedb, wb + 2 * WSZ, by, gy, y);
}

// Round 4
// 392.084 us; speedup vs baseline: 1.0741x; 1.0741x over previous
//
#include <hip/hip_runtime.h>

typedef unsigned short u16;
using bf16x8 = __attribute__((ext_vector_type(8))) __bf16;
using f32x4  = __attribute__((ext_vector_type(4))) float;

#define GL_TO_LDS(gp, sp) \
  __builtin_amdgcn_global_load_lds((const __attribute__((address_space(1))) void*)(gp), \
                                   (__attribute__((address_space(3))) void*)(sp), 16, 0, 0)

__device__ __forceinline__ u16 f2bf(float f){
  unsigned u = __builtin_bit_cast(unsigned, f);
  u += 0x7fffu + ((u >> 16) & 1u);
  return (u16)(u >> 16);
}
__device__ __forceinline__ float bf2f(u16 v){
  unsigned u = ((unsigned)v) << 16;
  return __builtin_bit_cast(float, u);
}

constexpr int SB = 4, SL = 4096, SD = 1024;
constexpr int GM = SB * SL, GN = SD, GK = SD;      // 16384 x 1024 x 1024
constexpr int NT = GK / 64;                        // 16 K-tiles of BK=64
constexpr int NCHUNK = 64, CH = SL / NCHUNK;       // 64 chunks of 64
constexpr float EPS_PHAZOR = 1e-5f;
constexpr float LOG2_SCALE = -9.965784284662087f;  // log2(0.001)

// ---------------- f32 -> bf16 conversion of x and the 4 weight matrices ----------------
__global__ __launch_bounds__(256) void k_convert(
    const float4* __restrict__ x4, const float4* __restrict__ wz4,
    const float4* __restrict__ wza4, const float4* __restrict__ wy4,
    const float4* __restrict__ wya4, u16* __restrict__ xb, u16* __restrict__ wb){
  int gid = blockIdx.x * 256 + threadIdx.x;   // each handles 8 floats
  const float4* src; u16* dst;
  if (gid < (GM * GK / 8)){
    src = x4 + (size_t)gid * 2; dst = xb + (size_t)gid * 8;
  } else {
    int g2 = gid - GM * GK / 8;
    int which = g2 >> 17, off = g2 & 0x1ffff;
    const float4* s4 = which == 0 ? wz4 : which == 1 ? wza4 : which == 2 ? wy4 : wya4;
    src = s4 + (size_t)off * 2; dst = wb + (size_t)which * (GK * GN) + (size_t)off * 8;
  }
  float4 a = src[0], b = src[1];
  u16 r[8] = {f2bf(a.x), f2bf(a.y), f2bf(a.z), f2bf(a.w),
              f2bf(b.x), f2bf(b.y), f2bf(b.z), f2bf(b.w)};
  *reinterpret_cast<uint4*>(dst) = *reinterpret_cast<const uint4*>(r);
}

// ---------------- 256x256 counted-vmcnt 4-phase GEMM, wave = 256 rows x 32 cols ----------------
// MODE 0: out(bf16) = f2bf(silu(acc + bias))          [gate producer]
// MODE 1: out(f32)  = (acc + bias) * bf2f(gate[..])   [final y]
// MODE 2: out(bf16) = f2bf((acc + bias) * bf2f(gate)) [z, bf16]
// A [M][K] bf16, W [N][K] bf16 (out = A @ W^T). Tile 256x256, BK=64, 8 waves, wave w owns
// cols [w*32, w*32+32) over all 256 rows -> UNIFORM A-half consumption (P0/P1: rows 0-127,
// P2/P3: rows 128-255) => counted vmcnt waits: vmcnt(8) at P1-end (A-hi of cur tile),
// vmcnt(2) at P3-end (B+A-lo of next tile). Pipe never drains to 0 in steady state.
// LDS 128 KiB (bytes): [0,32K) A sl0 | [32K,64K) A sl1 | [64K,96K) B sl0 | [96K,128K) B sl1.
// XOR swizzle: 16B slot s at row r holds logical k-chunk s^(r&7).

#define MM16(q) { _Pragma("unroll") for (int mf = 0; mf < 4; ++mf) \
  _Pragma("unroll") for (int nf = 0; nf < 2; ++nf) { \
    acc[(q)*4+mf][nf] = __builtin_amdgcn_mfma_f32_16x16x32_bf16(a[mf][0], bfr[nf][0], acc[(q)*4+mf][nf], 0, 0, 0); \
    acc[(q)*4+mf][nf] = __builtin_amdgcn_mfma_f32_16x16x32_bf16(a[mf][1], bfr[nf][1], acc[(q)*4+mf][nf], 0, 0, 0); } }

#define LDA4(q) { _Pragma("unroll") for (int mf = 0; mf < 4; ++mf) { \
    a[mf][0] = *reinterpret_cast<const bf16x8*>(&lds[ab + ((q)*64 + mf*16 + lr)*64 + pk0*8]); \
    a[mf][1] = *reinterpret_cast<const bf16x8*>(&lds[ab + ((q)*64 + mf*16 + lr)*64 + pk1*8]); } }

template<int MODE>
__global__ __launch_bounds__(512, 2) void k_gemm8(
    const u16* __restrict__ A, const u16* __restrict__ W,
    const float* __restrict__ bias, const u16* __restrict__ gate,
    void* __restrict__ outp){
  __shared__ u16 lds[65536];   // 128 KiB
  char* ldsb = (char*)lds;

  const int tid = threadIdx.x;
  const int w = tid >> 6, ln = tid & 63;
  const int lr = ln & 15, lg = ln >> 4;

  // XCD-aware bijective swizzle: 256 blocks, consecutive ids round-robin XCDs;
  // group the 4 bn-blocks of each bm (shared A panel) onto one XCD.
  const int lid = blockIdx.x;
  const int swz = (lid & 7) * 32 + (lid >> 3);
  const int bm = swz >> 2, bn = swz & 3;

  // ---- staging: 8 x 16B per thread per K-tile. Thread covers row r0+64j, slot s.
  // Issue order: B-lo, B-hi, A-lo, A-hi  (so vmcnt(2) leaves only A-hi in flight).
  const int r0 = tid >> 3, s = tid & 7;
  const int l8 = (s ^ (r0 & 7)) * 8;          // logical k offset stored in phys slot s
  const u16* Ab = A + (size_t)(bm * 256 + r0) * GK + l8;
  const u16* Wb = W + (size_t)(bn * 256 + r0) * GK + l8;
  const int dbase = r0 * 128 + s * 16;        // byte offset within a 32KB region

  const int pk0 = lg ^ (lr & 7);              // phys slot for k-chunk lg   (k-step 0)
  const int pk1 = (4 + lg) ^ (lr & 7);        // phys slot for k-chunk 4+lg (k-step 1)

  f32x4 acc[16][2] = {};

  // ---- prologue: stage tile 0 (region sl=0); need B+A-lo before P0 -> vmcnt(2) ----
  {
    #pragma unroll
    for (int u = 0; u < 8; ++u){
      const u16* gp = (u < 4 ? Wb : Ab) + (size_t)((u & 3) * 64) * GK;
      GL_TO_LDS(gp, ldsb + (u < 4 ? 65536 : 0) + dbase + (u & 3) * 8192);
    }
    asm volatile("s_waitcnt vmcnt(2)" ::: "memory");
    __builtin_amdgcn_s_barrier();
  }

  for (int t = 0; t < NT; ++t){
    const int sl = t & 1;
    const int ab = sl * 16384;                // A elem base (u16 units)
    const int bb = 32768 + sl * 16384;        // B elem base
    bf16x8 a[4][2], bfr[2][2];

    // ---- P0: 12 ds_reads (A q0 + B all) ; issue next tile's 8 stages ----
    LDA4(0);
    #pragma unroll
    for (int nf = 0; nf < 2; ++nf){
      bfr[nf][0] = *reinterpret_cast<const bf16x8*>(&lds[bb + (w*32 + nf*16 + lr)*64 + pk0*8]);
      bfr[nf][1] = *reinterpret_cast<const bf16x8*>(&lds[bb + (w*32 + nf*16 + lr)*64 + pk1*8]);
    }
    if (t + 1 < NT){
      const int so = (sl ^ 1) * 32768;        // next tile's region (bytes)
      #pragma unroll
      for (int u = 0; u < 8; ++u){
        const u16* gp = (u < 4 ? Wb : Ab) + (size_t)((u & 3) * 64) * GK + (t + 1) * 64;
        GL_TO_LDS(gp, ldsb + (u < 4 ? 65536 : 0) + so + dbase + (u & 3) * 8192);
      }
    }
    __builtin_amdgcn_s_barrier();
    __builtin_amdgcn_s_setprio(1); MM16(0); __builtin_amdgcn_s_setprio(0);
    __builtin_amdgcn_s_barrier();

    // ---- P1: A q1 ; end: vmcnt(8) guarantees cur tile's A-hi landed ----
    LDA4(1);
    __builtin_amdgcn_s_barrier();
    __builtin_amdgcn_s_setprio(1); MM16(1); __builtin_amdgcn_s_setprio(0);
    if (t + 1 < NT) asm volatile("s_waitcnt vmcnt(8)" ::: "memory");
    else            asm volatile("s_waitcnt vmcnt(0)" ::: "memory");
    __builtin_amdgcn_s_barrier();

    // ---- P2: A q2 (first A-hi consumer) ----
    LDA4(2);
    __builtin_amdgcn_s_barrier();
    __builtin_amdgcn_s_setprio(1); MM16(2); __builtin_amdgcn_s_setprio(0);
    __builtin_amdgcn_s_barrier();

    // ---- P3: A q3 ; end: vmcnt(2) guarantees next tile's B + A-lo landed ----
    LDA4(3);
    __builtin_amdgcn_s_barrier();
    __builtin_amdgcn_s_setprio(1); MM16(3); __builtin_amdgcn_s_setprio(0);
    if (t + 1 < NT) asm volatile("s_waitcnt vmcnt(2)" ::: "memory");
    __builtin_amdgcn_s_barrier();
  }

  // ---- epilogue: C/D frag layout col=lane&15, row=(lane>>4)*4+reg [m89] ----
  #pragma unroll
  for (int nf = 0; nf < 2; ++nf){
    const int col = bn * 256 + w * 32 + nf * 16 + lr;
    const float bb2 = bias[col];
    #pragma unroll
    for (int mf = 0; mf < 16; ++mf){
      const int rowb = bm * 256 + mf * 16 + lg * 4;
      f32x4 v = acc[mf][nf];
      if constexpr(MODE == 0){
        u16* gout = (u16*)outp;
        #pragma unroll
        for (int r = 0; r < 4; ++r){
          float p = v[r] + bb2;
          float sg = p / (1.f + __expf(-p));
          gout[(size_t)(rowb + r) * GN + col] = f2bf(sg);
        }
      } else if constexpr(MODE == 1){
        float* fout = (float*)outp;
        #pragma unroll
        for (int r = 0; r < 4; ++r){
          float g = bf2f(gate[(size_t)(rowb + r) * GN + col]);
          fout[(size_t)(rowb + r) * GN + col] = (v[r] + bb2) * g;
        }
      } else {
        u16* zout = (u16*)outp;
        #pragma unroll
        for (int r = 0; r < 4; ++r){
          float g = bf2f(gate[(size_t)(rowb + r) * GN + col]);
          zout[(size_t)(rowb + r) * GN + col] = f2bf((v[r] + bb2) * g);
        }
      }
    }
  }
}

// ---------------- chunked complex scan: h[l] = r*h[l-1] + z[l], h[-1] = last_conv ----------------
__global__ __launch_bounds__(256) void k_scan1(const u16* __restrict__ z, float2* __restrict__ carry){
  const int d = blockIdx.x * 256 + threadIdx.x;
  const int c = blockIdx.y, b = blockIdx.z;
  const float sc = exp2f(LOG2_SCALE * ((float)d * (1.0f / 1023.0f)));
  float si, co; sincosf(sc, &si, &co);
  const float er = expf(EPS_PHAZOR);
  const float rre = er * co, rim = er * si;
  const u16* zp = z + ((size_t)b * SL + (size_t)c * CH) * SD + d;
  float hre = 0.f, him = 0.f;
  #pragma unroll 8
  for (int i = 0; i < CH; i++){
    float zv = bf2f(zp[i * SD]);
    float nr = fmaf(rre, hre, fmaf(-rim, him, zv));
    him = fmaf(rre, him, rim * hre);
    hre = nr;
  }
  carry[(size_t)(b * NCHUNK + c) * SD + d] = make_float2(hre, him);
}

__global__ __launch_bounds__(256) void k_scan2(const float2* __restrict__ carry,
    const float* __restrict__ lcre, const float* __restrict__ lcim, float2* __restrict__ hin){
  const int idx = blockIdx.x * 256 + threadIdx.x;  // b*1024 + d
  const int b = idx >> 10, d = idx & 1023;
  const float sc = exp2f(LOG2_SCALE * ((float)d * (1.0f / 1023.0f)));
  float si, co; sincosf((float)CH * sc, &si, &co);
  const float eC = expf((float)CH * EPS_PHAZOR);
  const float Rre = eC * co, Rim = eC * si;
  float hre = lcre[d], him = lcim[d];
  for (int c = 0; c < NCHUNK; c++){
    const size_t o = (size_t)(b * NCHUNK + c) * SD + d;
    hin[o] = make_float2(hre, him);
    float2 cv = carry[o];
    float nr = fmaf(Rre, hre, fmaf(-Rim, him, cv.x));
    him = fmaf(Rre, him, fmaf(Rim, hre, cv.y));
    hre = nr;
  }
}

__global__ __launch_bounds__(256) void k_scan3(u16* __restrict__ zh, const float2* __restrict__ hin){
  const int d = blockIdx.x * 256 + threadIdx.x;
  const int c = blockIdx.y, b = blockIdx.z;
  const float sc = exp2f(LOG2_SCALE * ((float)d * (1.0f / 1023.0f)));
  float si, co; sincosf(sc, &si, &co);
  const float er = expf(EPS_PHAZOR);
  const float rre = er * co, rim = er * si;
  float2 h0 = hin[(size_t)(b * NCHUNK + c) * SD + d];
  float hre = h0.x, him = h0.y;
  u16* zp = zh + ((size_t)b * SL + (size_t)c * CH) * SD + d;
  #pragma unroll 8
  for (int i = 0; i < CH; i++){
    float zv = bf2f(zp[i * SD]);
    float nr = fmaf(rre, hre, fmaf(-rim, him, zv));
    him = fmaf(rre, him, rim * hre);
    hre = nr;
    zp[i * SD] = f2bf(hre);   // in-place: z -> Re(h) (bf16)
  }
}

// ---------------- RMSNorm row kernel (bf16 h -> bf16 normed) ----------------
__global__ __launch_bounds__(256) void k_rmsnorm(const u16* __restrict__ h,
    const float* __restrict__ nw, u16* __restrict__ outb){
  const int row = blockIdx.x, tid = threadIdx.x;
  const ushort4 hv = reinterpret_cast<const ushort4*>(h + (size_t)row * SD)[tid];
  float v0 = bf2f(hv.x), v1 = bf2f(hv.y), v2 = bf2f(hv.z), v3 = bf2f(hv.w);
  float ss = v0 * v0 + v1 * v1 + v2 * v2 + v3 * v3;
  #pragma unroll
  for (int o = 32; o; o >>= 1) ss += __shfl_down(ss, o, 64);
  __shared__ float red[5];
  const int lane = tid & 63, wid = tid >> 6;
  if (lane == 0) red[wid] = ss;
  __syncthreads();
  if (tid == 0) red[4] = rsqrtf((red[0] + red[1] + red[2] + red[3]) * (1.0f / (float)SD) + 1e-6f);
  __syncthreads();
  const float inv = red[4];
  const float4 w = reinterpret_cast<const float4*>(nw)[tid];
  u16 r[4] = { f2bf(v0 * inv * w.x), f2bf(v1 * inv * w.y),
               f2bf(v2 * inv * w.z), f2bf(v3 * inv * w.w) };
  reinterpret_cast<ushort4*>(outb + (size_t)row * SD)[tid] = *reinterpret_cast<const ushort4*>(r);
}

// ---------------- launch ----------------
extern "C" void kernel_launch(void* const* d_in, const int* in_sizes, int n_in,
                              void* d_out, int out_size, void* d_ws, size_t ws_size,
                              hipStream_t stream){
  const float* x    = (const float*)d_in[0];
  const float* Wz   = (const float*)d_in[1];
  const float* bz   = (const float*)d_in[2];
  const float* Wza  = (const float*)d_in[3];
  const float* bza  = (const float*)d_in[4];
  const float* Wy   = (const float*)d_in[5];
  const float* by   = (const float*)d_in[6];
  const float* Wya  = (const float*)d_in[7];
  const float* bya  = (const float*)d_in[8];
  const float* nw   = (const float*)d_in[9];
  const float* lcre = (const float*)d_in[10];
  const float* lcim = (const float*)d_in[11];

  char* ws = (char*)d_ws;
  // workspace (136 MiB total — proven footprint):
  //  [0,32M)    xb (bf16 x); dead after the 3 input GEMMs -> normedb reuses it
  //  [32M,40M)  wb: Wz,Wza,Wy,Wya bf16 (2 MiB each)
  //  [40M,72M)  gz (bf16 gate for z, 32 MiB); dead after gemm_z -> carry/hin overlay
  //  [72M,104M) gy (bf16 gate for y, 32 MiB); live until final gemm
  //  [104M,136M) zb (bf16 z -> Re(h) in place, 32 MiB)
  u16*    xb      = (u16*)(ws);
  u16*    normedb = (u16*)(ws);
  u16*    wb      = (u16*)(ws + (32ull << 20));
  u16*    gz      = (u16*)(ws + (40ull << 20));
  float2* carry   = (float2*)(ws + (40ull << 20));
  float2* hin     = (float2*)(ws + (42ull << 20));
  u16*    gy      = (u16*)(ws + (72ull << 20));
  u16*    zb      = (u16*)(ws + (104ull << 20));
  float*  y       = (float*)d_out;

  const size_t WSZ = (size_t)GK * GN;  // 1M elements per weight

  k_convert<<<10240, 256, 0, stream>>>((const float4*)x, (const float4*)Wz, (const float4*)Wza,
                                       (const float4*)Wy, (const float4*)Wya, xb, wb);
  // gy = silu(x@Wya^T + bya)
  k_gemm8<0><<<256, 512, 0, stream>>>(xb, wb + 3 * WSZ, bya, nullptr, gy);
  // gz = silu(x@Wza^T + bza)
  k_gemm8<0><<<256, 512, 0, stream>>>(xb, wb + 1 * WSZ, bza, nullptr, gz);
  // z = (x@Wz^T + bz) * gz   (bf16)
  k_gemm8<2><<<256, 512, 0, stream>>>(xb, wb + 0 * WSZ, bz, gz, zb);
  k_scan1<<<dim3(SD / 256, NCHUNK, SB), 256, 0, stream>>>(zb, carry);
  k_scan2<<<(SB * SD) / 256, 256, 0, stream>>>(carry, lcre, lcim, hin);
  k_scan3<<<dim3(SD / 256, NCHUNK, SB), 256, 0, stream>>>(zb, hin);
  k_rmsnorm<<<GM, 256, 0, stream>>>(zb, nw, normedb);
  // y = (normed@Wy^T + by) * gy
  k_gemm8<1><<<256, 512, 0, stream>>>(normedb, wb + 2 * WSZ, by, gy, y);
}

// Round 6
// 335.359 us; speedup vs baseline: 1.2558x; 1.1691x over previous
//
#include <hip/hip_runtime.h>

typedef unsigned short u16;
using bf16x8 = __attribute__((ext_vector_type(8))) __bf16;
using f32x4  = __attribute__((ext_vector_type(4))) float;

#define GL_TO_LDS(gp, sp) \
  __builtin_amdgcn_global_load_lds((const __attribute__((address_space(1))) void*)(gp), \
                                   (__attribute__((address_space(3))) void*)(sp), 16, 0, 0)

#define MFMA_BF16 __builtin_amdgcn_mfma_f32_16x16x32_bf16

__device__ __forceinline__ u16 f2bf(float f){
  unsigned u = __builtin_bit_cast(unsigned, f);
  u += 0x7fffu + ((u >> 16) & 1u);
  return (u16)(u >> 16);
}
__device__ __forceinline__ float bf2f(u16 v){
  unsigned u = ((unsigned)v) << 16;
  return __builtin_bit_cast(float, u);
}

constexpr int SB = 4, SL = 4096, SD = 1024;
constexpr int GM = SB * SL, GN = SD, GK = SD;      // 16384 x 1024 x 1024
constexpr int NT = GK / 64;                        // 16 K-tiles of BK=64
constexpr int NCHUNK = 64, CH = SL / NCHUNK;       // 64 chunks of 64
constexpr float EPS_PHAZOR = 1e-5f;
constexpr float LOG2_SCALE = -9.965784284662087f;  // log2(0.001)

// ---------------- f32 -> bf16 conversion of x and the 4 weight matrices ----------------
__global__ __launch_bounds__(256) void k_convert(
    const float4* __restrict__ x4, const float4* __restrict__ wz4,
    const float4* __restrict__ wza4, const float4* __restrict__ wy4,
    const float4* __restrict__ wya4, u16* __restrict__ xb, u16* __restrict__ wb){
  int gid = blockIdx.x * 256 + threadIdx.x;   // each handles 8 floats
  const float4* src; u16* dst;
  if (gid < (GM * GK / 8)){
    src = x4 + (size_t)gid * 2; dst = xb + (size_t)gid * 8;
  } else {
    int g2 = gid - GM * GK / 8;
    int which = g2 >> 17, off = g2 & 0x1ffff;
    const float4* s4 = which == 0 ? wz4 : which == 1 ? wza4 : which == 2 ? wy4 : wya4;
    src = s4 + (size_t)off * 2; dst = wb + (size_t)which * (GK * GN) + (size_t)off * 8;
  }
  float4 a = src[0], b = src[1];
  u16 r[8] = {f2bf(a.x), f2bf(a.y), f2bf(a.z), f2bf(a.w),
              f2bf(b.x), f2bf(b.y), f2bf(b.z), f2bf(b.w)};
  *reinterpret_cast<uint4*>(dst) = *reinterpret_cast<const uint4*>(r);
}

// Shared geometry for the 128x128 / BK=64 GEMMs:
// 4 waves (2x2), wave owns 64x64 via 4x4 frags. LDS tiles [128 rows][8 x 16B slots],
// XOR swizzle: phys slot s at row r holds logical k-chunk s^(r&7) (conflict-free b128 reads).
// XCD-bijective grid map: 1024 blocks, XCD i gets bm in [i*16,(i+1)*16) x all 8 bn.

// ---------------- dual GEMM -> z = (A@W0^T + b0) * silu(A@W1^T + b1), bf16 out ----------------
__global__ __launch_bounds__(256, 2) void k_gdual(
    const u16* __restrict__ A, const u16* __restrict__ W0, const u16* __restrict__ W1,
    const float* __restrict__ bias0, const float* __restrict__ bias1,
    u16* __restrict__ out){
  __shared__ u16 sA[8192], sB0[8192], sB1[8192];
  const int tid = threadIdx.x;
  const int w = tid >> 6, ln = tid & 63;
  const int wm = w >> 1, wn = w & 1;
  const int lr = ln & 15, lg = ln >> 4;
  const int lid = blockIdx.x;
  const int swz = (lid & 7) * 128 + (lid >> 3);
  const int bm = swz >> 3, bn = swz & 7;

  size_t soff[4]; int dof[4];
  #pragma unroll
  for (int j = 0; j < 4; ++j){
    int g = j * 256 + tid, r = g >> 3, s = g & 7;
    soff[j] = (size_t)r * GK + (size_t)((s ^ (r & 7)) * 8);
    dof[j] = g * 16;
  }
  const u16* Ab  = A  + (size_t)(bm * 128) * GK;
  const u16* W0b = W0 + (size_t)(bn * 128) * GK;
  const u16* W1b = W1 + (size_t)(bn * 128) * GK;

  f32x4 acc0[4][4] = {}, acc1[4][4] = {};

  for (int t = 0; t < NT; ++t){
    const int k0 = t * 64;
    #pragma unroll
    for (int j = 0; j < 4; ++j){
      GL_TO_LDS(Ab  + soff[j] + k0, (char*)sA  + dof[j]);
      GL_TO_LDS(W0b + soff[j] + k0, (char*)sB0 + dof[j]);
      GL_TO_LDS(W1b + soff[j] + k0, (char*)sB1 + dof[j]);
    }
    __syncthreads();

    bf16x8 a[4][2], b[4][2];
    #pragma unroll
    for (int mf = 0; mf < 4; ++mf){
      const int row = wm * 64 + mf * 16 + lr;
      #pragma unroll
      for (int ks = 0; ks < 2; ++ks)
        a[mf][ks] = *reinterpret_cast<const bf16x8*>(&sA[row * 64 + ((ks * 4 + lg) ^ (row & 7)) * 8]);
    }
    #pragma unroll
    for (int nf = 0; nf < 4; ++nf){
      const int row = wn * 64 + nf * 16 + lr;
      #pragma unroll
      for (int ks = 0; ks < 2; ++ks)
        b[nf][ks] = *reinterpret_cast<const bf16x8*>(&sB0[row * 64 + ((ks * 4 + lg) ^ (row & 7)) * 8]);
    }
    #pragma unroll
    for (int mf = 0; mf < 4; ++mf)
      #pragma unroll
      for (int nf = 0; nf < 4; ++nf){
        acc0[mf][nf] = MFMA_BF16(a[mf][0], b[nf][0], acc0[mf][nf], 0, 0, 0);
        acc0[mf][nf] = MFMA_BF16(a[mf][1], b[nf][1], acc0[mf][nf], 0, 0, 0);
      }
    #pragma unroll
    for (int nf = 0; nf < 4; ++nf){
      const int row = wn * 64 + nf * 16 + lr;
      #pragma unroll
      for (int ks = 0; ks < 2; ++ks)
        b[nf][ks] = *reinterpret_cast<const bf16x8*>(&sB1[row * 64 + ((ks * 4 + lg) ^ (row & 7)) * 8]);
    }
    #pragma unroll
    for (int mf = 0; mf < 4; ++mf)
      #pragma unroll
      for (int nf = 0; nf < 4; ++nf){
        acc1[mf][nf] = MFMA_BF16(a[mf][0], b[nf][0], acc1[mf][nf], 0, 0, 0);
        acc1[mf][nf] = MFMA_BF16(a[mf][1], b[nf][1], acc1[mf][nf], 0, 0, 0);
      }
    __syncthreads();
  }

  // epilogue: C/D layout col=lane&15, row=(lane>>4)*4+reg [m89]
  #pragma unroll
  for (int nf = 0; nf < 4; ++nf){
    const int col = bn * 128 + wn * 64 + nf * 16 + lr;
    const float bb0 = bias0[col], bb1 = bias1[col];
    #pragma unroll
    for (int mf = 0; mf < 4; ++mf){
      const int rowb = bm * 128 + wm * 64 + mf * 16 + lg * 4;
      f32x4 v0 = acc0[mf][nf], v1 = acc1[mf][nf];
      #pragma unroll
      for (int r = 0; r < 4; ++r){
        float p1 = v1[r] + bb1;
        float sg = p1 / (1.f + __expf(-p1));
        out[(size_t)(rowb + r) * GN + col] = f2bf((v0[r] + bb0) * sg);
      }
    }
  }
}

// ---------------- single GEMM: MODE 0 -> bf16 silu(acc+b); MODE 1 -> f32 (acc+b)*gate ----------------
template<int MODE>
__global__ __launch_bounds__(256, 3) void k_gsingle(
    const u16* __restrict__ A, const u16* __restrict__ W,
    const float* __restrict__ bias, const u16* __restrict__ gate,
    void* __restrict__ outp){
  __shared__ u16 sA[8192], sB[8192];
  const int tid = threadIdx.x;
  const int w = tid >> 6, ln = tid & 63;
  const int wm = w >> 1, wn = w & 1;
  const int lr = ln & 15, lg = ln >> 4;
  const int lid = blockIdx.x;
  const int swz = (lid & 7) * 128 + (lid >> 3);
  const int bm = swz >> 3, bn = swz & 7;

  size_t soff[4]; int dof[4];
  #pragma unroll
  for (int j = 0; j < 4; ++j){
    int g = j * 256 + tid, r = g >> 3, s = g & 7;
    soff[j] = (size_t)r * GK + (size_t)((s ^ (r & 7)) * 8);
    dof[j] = g * 16;
  }
  const u16* Ab = A + (size_t)(bm * 128) * GK;
  const u16* Wb = W + (size_t)(bn * 128) * GK;

  f32x4 acc[4][4] = {};

  for (int t = 0; t < NT; ++t){
    const int k0 = t * 64;
    #pragma unroll
    for (int j = 0; j < 4; ++j){
      GL_TO_LDS(Ab + soff[j] + k0, (char*)sA + dof[j]);
      GL_TO_LDS(Wb + soff[j] + k0, (char*)sB + dof[j]);
    }
    __syncthreads();

    bf16x8 a[4][2], b[4][2];
    #pragma unroll
    for (int mf = 0; mf < 4; ++mf){
      const int row = wm * 64 + mf * 16 + lr;
      #pragma unroll
      for (int ks = 0; ks < 2; ++ks)
        a[mf][ks] = *reinterpret_cast<const bf16x8*>(&sA[row * 64 + ((ks * 4 + lg) ^ (row & 7)) * 8]);
    }
    #pragma unroll
    for (int nf = 0; nf < 4; ++nf){
      const int row = wn * 64 + nf * 16 + lr;
      #pragma unroll
      for (int ks = 0; ks < 2; ++ks)
        b[nf][ks] = *reinterpret_cast<const bf16x8*>(&sB[row * 64 + ((ks * 4 + lg) ^ (row & 7)) * 8]);
    }
    #pragma unroll
    for (int mf = 0; mf < 4; ++mf)
      #pragma unroll
      for (int nf = 0; nf < 4; ++nf){
        acc[mf][nf] = MFMA_BF16(a[mf][0], b[nf][0], acc[mf][nf], 0, 0, 0);
        acc[mf][nf] = MFMA_BF16(a[mf][1], b[nf][1], acc[mf][nf], 0, 0, 0);
      }
    __syncthreads();
  }

  #pragma unroll
  for (int nf = 0; nf < 4; ++nf){
    const int col = bn * 128 + wn * 64 + nf * 16 + lr;
    const float bb = bias[col];
    #pragma unroll
    for (int mf = 0; mf < 4; ++mf){
      const int rowb = bm * 128 + wm * 64 + mf * 16 + lg * 4;
      f32x4 v = acc[mf][nf];
      if constexpr(MODE == 0){
        u16* gout = (u16*)outp;
        #pragma unroll
        for (int r = 0; r < 4; ++r){
          float p = v[r] + bb;
          gout[(size_t)(rowb + r) * GN + col] = f2bf(p / (1.f + __expf(-p)));
        }
      } else {
        float* fout = (float*)outp;
        #pragma unroll
        for (int r = 0; r < 4; ++r){
          float g = bf2f(gate[(size_t)(rowb + r) * GN + col]);
          fout[(size_t)(rowb + r) * GN + col] = (v[r] + bb) * g;
        }
      }
    }
  }
}

// ---------------- chunked complex scan: h[l] = r*h[l-1] + z[l], h[-1] = last_conv ----------------
__global__ __launch_bounds__(256) void k_scan1(const u16* __restrict__ z, float2* __restrict__ carry){
  const int d = blockIdx.x * 256 + threadIdx.x;
  const int c = blockIdx.y, b = blockIdx.z;
  const float sc = exp2f(LOG2_SCALE * ((float)d * (1.0f / 1023.0f)));
  float si, co; sincosf(sc, &si, &co);
  const float er = expf(EPS_PHAZOR);
  const float rre = er * co, rim = er * si;
  const u16* zp = z + ((size_t)b * SL + (size_t)c * CH) * SD + d;
  float hre = 0.f, him = 0.f;
  #pragma unroll 8
  for (int i = 0; i < CH; i++){
    float zv = bf2f(zp[i * SD]);
    float nr = fmaf(rre, hre, fmaf(-rim, him, zv));
    him = fmaf(rre, him, rim * hre);
    hre = nr;
  }
  carry[(size_t)(b * NCHUNK + c) * SD + d] = make_float2(hre, him);
}

__global__ __launch_bounds__(256) void k_scan2(const float2* __restrict__ carry,
    const float* __restrict__ lcre, const float* __restrict__ lcim, float2* __restrict__ hin){
  const int idx = blockIdx.x * 256 + threadIdx.x;  // b*1024 + d
  const int b = idx >> 10, d = idx & 1023;
  const float sc = exp2f(LOG2_SCALE * ((float)d * (1.0f / 1023.0f)));
  float si, co; sincosf((float)CH * sc, &si, &co);
  const float eC = expf((float)CH * EPS_PHAZOR);
  const float Rre = eC * co, Rim = eC * si;
  // prefetch all carries (breaks the dependent-load chain; 128 VGPRs, fully static indices)
  float2 cv[NCHUNK];
  const float2* cp = carry + (size_t)b * NCHUNK * SD + d;
  #pragma unroll
  for (int c = 0; c < NCHUNK; c++) cv[c] = cp[(size_t)c * SD];
  float hre = lcre[d], him = lcim[d];
  float2* hp = hin + (size_t)b * NCHUNK * SD + d;
  #pragma unroll
  for (int c = 0; c < NCHUNK; c++){
    hp[(size_t)c * SD] = make_float2(hre, him);
    float nr = fmaf(Rre, hre, fmaf(-Rim, him, cv[c].x));
    him = fmaf(Rre, him, fmaf(Rim, hre, cv[c].y));
    hre = nr;
  }
}

__global__ __launch_bounds__(256) void k_scan3(u16* __restrict__ zh, const float2* __restrict__ hin){
  const int d = blockIdx.x * 256 + threadIdx.x;
  const int c = blockIdx.y, b = blockIdx.z;
  const float sc = exp2f(LOG2_SCALE * ((float)d * (1.0f / 1023.0f)));
  float si, co; sincosf(sc, &si, &co);
  const float er = expf(EPS_PHAZOR);
  const float rre = er * co, rim = er * si;
  float2 h0 = hin[(size_t)(b * NCHUNK + c) * SD + d];
  float hre = h0.x, him = h0.y;
  u16* zp = zh + ((size_t)b * SL + (size_t)c * CH) * SD + d;
  #pragma unroll 8
  for (int i = 0; i < CH; i++){
    float zv = bf2f(zp[i * SD]);
    float nr = fmaf(rre, hre, fmaf(-rim, him, zv));
    him = fmaf(rre, him, rim * hre);
    hre = nr;
    zp[i * SD] = f2bf(hre);   // in-place: z -> Re(h) (bf16)
  }
}

// ---------------- RMSNorm row kernel (bf16 h -> bf16 normed) ----------------
__global__ __launch_bounds__(256) void k_rmsnorm(const u16* __restrict__ h,
    const float* __restrict__ nw, u16* __restrict__ outb){
  const int row = blockIdx.x, tid = threadIdx.x;
  const ushort4 hv = reinterpret_cast<const ushort4*>(h + (size_t)row * SD)[tid];
  float v0 = bf2f(hv.x), v1 = bf2f(hv.y), v2 = bf2f(hv.z), v3 = bf2f(hv.w);
  float ss = v0 * v0 + v1 * v1 + v2 * v2 + v3 * v3;
  #pragma unroll
  for (int o = 32; o; o >>= 1) ss += __shfl_down(ss, o, 64);
  __shared__ float red[5];
  const int lane = tid & 63, wid = tid >> 6;
  if (lane == 0) red[wid] = ss;
  __syncthreads();
  if (tid == 0) red[4] = rsqrtf((red[0] + red[1] + red[2] + red[3]) * (1.0f / (float)SD) + 1e-6f);
  __syncthreads();
  const float inv = red[4];
  const float4 w = reinterpret_cast<const float4*>(nw)[tid];
  u16 r[4] = { f2bf(v0 * inv * w.x), f2bf(v1 * inv * w.y),
               f2bf(v2 * inv * w.z), f2bf(v3 * inv * w.w) };
  reinterpret_cast<ushort4*>(outb + (size_t)row * SD)[tid] = *reinterpret_cast<const ushort4*>(r);
}

// ---------------- launch ----------------
extern "C" void kernel_launch(void* const* d_in, const int* in_sizes, int n_in,
                              void* d_out, int out_size, void* d_ws, size_t ws_size,
                              hipStream_t stream){
  const float* x    = (const float*)d_in[0];
  const float* Wz   = (const float*)d_in[1];
  const float* bz   = (const float*)d_in[2];
  const float* Wza  = (const float*)d_in[3];
  const float* bza  = (const float*)d_in[4];
  const float* Wy   = (const float*)d_in[5];
  const float* by   = (const float*)d_in[6];
  const float* Wya  = (const float*)d_in[7];
  const float* bya  = (const float*)d_in[8];
  const float* nw   = (const float*)d_in[9];
  const float* lcre = (const float*)d_in[10];
  const float* lcim = (const float*)d_in[11];

  char* ws = (char*)d_ws;
  // workspace (108 MiB):
  //  [0,32M)    xb (bf16 x); dead after gy-GEMM -> normedb reuses it
  //  [32M,40M)  wb: Wz,Wza,Wy,Wya bf16 (2 MiB each)
  //  [40M,72M)  gy (bf16 gate for y); live until final gemm
  //  [72M,104M) zb (bf16 z -> Re(h) in place)
  //  [104M,106M) carry ; [106M,108M) hin
  u16*    xb      = (u16*)(ws);
  u16*    normedb = (u16*)(ws);
  u16*    wb      = (u16*)(ws + (32ull << 20));
  u16*    gy      = (u16*)(ws + (40ull << 20));
  u16*    zb      = (u16*)(ws + (72ull << 20));
  float2* carry   = (float2*)(ws + (104ull << 20));
  float2* hin     = (float2*)(ws + (106ull << 20));
  float*  y       = (float*)d_out;

  const size_t WSZ = (size_t)GK * GN;  // 1M elements per weight

  k_convert<<<10240, 256, 0, stream>>>((const float4*)x, (const float4*)Wz, (const float4*)Wza,
                                       (const float4*)Wy, (const float4*)Wya, xb, wb);
  // z = (x@Wz^T + bz) * silu(x@Wza^T + bza)   [bf16, no gz intermediate]
  k_gdual<<<1024, 256, 0, stream>>>(xb, wb + 0 * WSZ, wb + 1 * WSZ, bz, bza, zb);
  // gy = silu(x@Wya^T + bya)
  k_gsingle<0><<<1024, 256, 0, stream>>>(xb, wb + 3 * WSZ, bya, nullptr, gy);
  k_scan1<<<dim3(SD / 256, NCHUNK, SB), 256, 0, stream>>>(zb, carry);
  k_scan2<<<(SB * SD) / 256, 256, 0, stream>>>(carry, lcre, lcim, hin);
  k_scan3<<<dim3(SD / 256, NCHUNK, SB), 256, 0, stream>>>(zb, hin);
  k_rmsnorm<<<GM, 256, 0, stream>>>(zb, nw, normedb);
  // y = (normed@Wy^T + by) * gy
  k_gsingle<1><<<1024, 256, 0, stream>>>(normedb, wb + 2 * WSZ, by, gy, y);
}

// Round 7
// 331.302 us; speedup vs baseline: 1.2711x; 1.0122x over previous
//
#include <hip/hip_runtime.h>

typedef unsigned short u16;
using bf16x8 = __attribute__((ext_vector_type(8))) __bf16;
using f32x4  = __attribute__((ext_vector_type(4))) float;

#define GL_TO_LDS(gp, sp) \
  __builtin_amdgcn_global_load_lds((const __attribute__((address_space(1))) void*)(gp), \
                                   (__attribute__((address_space(3))) void*)(sp), 16, 0, 0)

#define MFMA_BF16 __builtin_amdgcn_mfma_f32_16x16x32_bf16

__device__ __forceinline__ u16 f2bf(float f){
  unsigned u = __builtin_bit_cast(unsigned, f);
  u += 0x7fffu + ((u >> 16) & 1u);
  return (u16)(u >> 16);
}
__device__ __forceinline__ float bf2f(u16 v){
  unsigned u = ((unsigned)v) << 16;
  return __builtin_bit_cast(float, u);
}

constexpr int SB = 4, SL = 4096, SD = 1024;
constexpr int GM = SB * SL, GN = SD, GK = SD;      // 16384 x 1024 x 1024
constexpr int NT = GK / 64;                        // 16 K-tiles of BK=64
constexpr int NCHUNK = 64, CH = SL / NCHUNK;       // 64 chunks of 64
constexpr float EPS_PHAZOR = 1e-5f;
constexpr float LOG2_SCALE = -9.965784284662087f;  // log2(0.001)

// ---------------- f32 -> bf16 conversion; Wy is pre-scaled by norm_w along k ----------------
__global__ __launch_bounds__(256) void k_convert(
    const float4* __restrict__ x4, const float4* __restrict__ wz4,
    const float4* __restrict__ wza4, const float4* __restrict__ wy4,
    const float4* __restrict__ wya4, const float4* __restrict__ nw4,
    u16* __restrict__ xb, u16* __restrict__ wb){
  int gid = blockIdx.x * 256 + threadIdx.x;   // each handles 8 floats
  const float4* src; u16* dst;
  bool scale = false; int off = 0;
  if (gid < (GM * GK / 8)){
    src = x4 + (size_t)gid * 2; dst = xb + (size_t)gid * 8;
  } else {
    int g2 = gid - GM * GK / 8;
    int which = g2 >> 17; off = g2 & 0x1ffff;
    const float4* s4 = which == 0 ? wz4 : which == 1 ? wza4 : which == 2 ? wy4 : wya4;
    src = s4 + (size_t)off * 2; dst = wb + (size_t)which * (GK * GN) + (size_t)off * 8;
    scale = (which == 2);   // Wy' = norm_w (k-dim) * Wy
  }
  float4 a = src[0], b = src[1];
  if (scale){
    float4 na = nw4[(off & 127) * 2], nb = nw4[(off & 127) * 2 + 1];
    a.x *= na.x; a.y *= na.y; a.z *= na.z; a.w *= na.w;
    b.x *= nb.x; b.y *= nb.y; b.z *= nb.z; b.w *= nb.w;
  }
  u16 r[8] = {f2bf(a.x), f2bf(a.y), f2bf(a.z), f2bf(a.w),
              f2bf(b.x), f2bf(b.y), f2bf(b.z), f2bf(b.w)};
  *reinterpret_cast<uint4*>(dst) = *reinterpret_cast<const uint4*>(r);
}

// Shared geometry (128x128 / BK=64): 4 waves (2x2), wave owns 64x64 via 4x4 frags.
// LDS tiles [128 rows][8 x 16B slots], XOR swizzle: phys slot s at row r holds logical
// k-chunk s^(r&7) (conflict-free ds_read_b128). XCD-bijective map: 1024 blocks,
// XCD i gets bm in [i*16,(i+1)*16) x all 8 bn (A panel fetched once per XCD).

// ---------------- dual GEMM -> z = (A@W0^T + b0) * silu(A@W1^T + b1), bf16 out ----------------
__global__ __launch_bounds__(256, 2) void k_gdual(
    const u16* __restrict__ A, const u16* __restrict__ W0, const u16* __restrict__ W1,
    const float* __restrict__ bias0, const float* __restrict__ bias1,
    u16* __restrict__ out){
  __shared__ u16 sA[8192], sB0[8192], sB1[8192];
  const int tid = threadIdx.x;
  const int w = tid >> 6, ln = tid & 63;
  const int wm = w >> 1, wn = w & 1;
  const int lr = ln & 15, lg = ln >> 4;
  const int lid = blockIdx.x;
  const int swz = (lid & 7) * 128 + (lid >> 3);
  const int bm = swz >> 3, bn = swz & 7;

  size_t soff[4]; int dof[4];
  #pragma unroll
  for (int j = 0; j < 4; ++j){
    int g = j * 256 + tid, r = g >> 3, s = g & 7;
    soff[j] = (size_t)r * GK + (size_t)((s ^ (r & 7)) * 8);
    dof[j] = g * 16;
  }
  const u16* Ab  = A  + (size_t)(bm * 128) * GK;
  const u16* W0b = W0 + (size_t)(bn * 128) * GK;
  const u16* W1b = W1 + (size_t)(bn * 128) * GK;

  f32x4 acc0[4][4] = {}, acc1[4][4] = {};

  for (int t = 0; t < NT; ++t){
    const int k0 = t * 64;
    #pragma unroll
    for (int j = 0; j < 4; ++j){
      GL_TO_LDS(Ab  + soff[j] + k0, (char*)sA  + dof[j]);
      GL_TO_LDS(W0b + soff[j] + k0, (char*)sB0 + dof[j]);
      GL_TO_LDS(W1b + soff[j] + k0, (char*)sB1 + dof[j]);
    }
    __syncthreads();

    bf16x8 a[4][2], b[4][2];
    #pragma unroll
    for (int mf = 0; mf < 4; ++mf){
      const int row = wm * 64 + mf * 16 + lr;
      #pragma unroll
      for (int ks = 0; ks < 2; ++ks)
        a[mf][ks] = *reinterpret_cast<const bf16x8*>(&sA[row * 64 + ((ks * 4 + lg) ^ (row & 7)) * 8]);
    }
    #pragma unroll
    for (int nf = 0; nf < 4; ++nf){
      const int row = wn * 64 + nf * 16 + lr;
      #pragma unroll
      for (int ks = 0; ks < 2; ++ks)
        b[nf][ks] = *reinterpret_cast<const bf16x8*>(&sB0[row * 64 + ((ks * 4 + lg) ^ (row & 7)) * 8]);
    }
    #pragma unroll
    for (int mf = 0; mf < 4; ++mf)
      #pragma unroll
      for (int nf = 0; nf < 4; ++nf){
        acc0[mf][nf] = MFMA_BF16(a[mf][0], b[nf][0], acc0[mf][nf], 0, 0, 0);
        acc0[mf][nf] = MFMA_BF16(a[mf][1], b[nf][1], acc0[mf][nf], 0, 0, 0);
      }
    #pragma unroll
    for (int nf = 0; nf < 4; ++nf){
      const int row = wn * 64 + nf * 16 + lr;
      #pragma unroll
      for (int ks = 0; ks < 2; ++ks)
        b[nf][ks] = *reinterpret_cast<const bf16x8*>(&sB1[row * 64 + ((ks * 4 + lg) ^ (row & 7)) * 8]);
    }
    #pragma unroll
    for (int mf = 0; mf < 4; ++mf)
      #pragma unroll
      for (int nf = 0; nf < 4; ++nf){
        acc1[mf][nf] = MFMA_BF16(a[mf][0], b[nf][0], acc1[mf][nf], 0, 0, 0);
        acc1[mf][nf] = MFMA_BF16(a[mf][1], b[nf][1], acc1[mf][nf], 0, 0, 0);
      }
    __syncthreads();
  }

  // epilogue: C/D layout col=lane&15, row=(lane>>4)*4+reg [m89]
  #pragma unroll
  for (int nf = 0; nf < 4; ++nf){
    const int col = bn * 128 + wn * 64 + nf * 16 + lr;
    const float bb0 = bias0[col], bb1 = bias1[col];
    #pragma unroll
    for (int mf = 0; mf < 4; ++mf){
      const int rowb = bm * 128 + wm * 64 + mf * 16 + lg * 4;
      f32x4 v0 = acc0[mf][nf], v1 = acc1[mf][nf];
      #pragma unroll
      for (int r = 0; r < 4; ++r){
        float p1 = v1[r] + bb1;
        float sg = p1 / (1.f + __expf(-p1));
        out[(size_t)(rowb + r) * GN + col] = f2bf((v0[r] + bb0) * sg);
      }
    }
  }
}

// ---------------- final dual-A GEMM: y = (inv[row]*(A0@W0^T) + b0) * silu(A1@W1^T + b1) ----------------
__global__ __launch_bounds__(256, 2) void k_gfinal(
    const u16* __restrict__ A0, const u16* __restrict__ A1,
    const u16* __restrict__ W0, const u16* __restrict__ W1,
    const float* __restrict__ bias0, const float* __restrict__ bias1,
    const float* __restrict__ ssq, float* __restrict__ out){
  __shared__ u16 sA0[8192], sA1[8192], sB0[8192], sB1[8192];   // 64 KiB
  const int tid = threadIdx.x;
  const int w = tid >> 6, ln = tid & 63;
  const int wm = w >> 1, wn = w & 1;
  const int lr = ln & 15, lg = ln >> 4;
  const int lid = blockIdx.x;
  const int swz = (lid & 7) * 128 + (lid >> 3);
  const int bm = swz >> 3, bn = swz & 7;

  size_t soff[4]; int dof[4];
  #pragma unroll
  for (int j = 0; j < 4; ++j){
    int g = j * 256 + tid, r = g >> 3, s = g & 7;
    soff[j] = (size_t)r * GK + (size_t)((s ^ (r & 7)) * 8);
    dof[j] = g * 16;
  }
  const u16* A0b = A0 + (size_t)(bm * 128) * GK;
  const u16* A1b = A1 + (size_t)(bm * 128) * GK;
  const u16* W0b = W0 + (size_t)(bn * 128) * GK;
  const u16* W1b = W1 + (size_t)(bn * 128) * GK;

  f32x4 acc0[4][4] = {}, acc1[4][4] = {};

  for (int t = 0; t < NT; ++t){
    const int k0 = t * 64;
    #pragma unroll
    for (int j = 0; j < 4; ++j){
      GL_TO_LDS(A0b + soff[j] + k0, (char*)sA0 + dof[j]);
      GL_TO_LDS(A1b + soff[j] + k0, (char*)sA1 + dof[j]);
      GL_TO_LDS(W0b + soff[j] + k0, (char*)sB0 + dof[j]);
      GL_TO_LDS(W1b + soff[j] + k0, (char*)sB1 + dof[j]);
    }
    __syncthreads();

    bf16x8 a[4][2], b[4][2];
    // pass 0: acc0 += A0 @ B0
    #pragma unroll
    for (int mf = 0; mf < 4; ++mf){
      const int row = wm * 64 + mf * 16 + lr;
      #pragma unroll
      for (int ks = 0; ks < 2; ++ks)
        a[mf][ks] = *reinterpret_cast<const bf16x8*>(&sA0[row * 64 + ((ks * 4 + lg) ^ (row & 7)) * 8]);
    }
    #pragma unroll
    for (int nf = 0; nf < 4; ++nf){
      const int row = wn * 64 + nf * 16 + lr;
      #pragma unroll
      for (int ks = 0; ks < 2; ++ks)
        b[nf][ks] = *reinterpret_cast<const bf16x8*>(&sB0[row * 64 + ((ks * 4 + lg) ^ (row & 7)) * 8]);
    }
    #pragma unroll
    for (int mf = 0; mf < 4; ++mf)
      #pragma unroll
      for (int nf = 0; nf < 4; ++nf){
        acc0[mf][nf] = MFMA_BF16(a[mf][0], b[nf][0], acc0[mf][nf], 0, 0, 0);
        acc0[mf][nf] = MFMA_BF16(a[mf][1], b[nf][1], acc0[mf][nf], 0, 0, 0);
      }
    // pass 1: acc1 += A1 @ B1
    #pragma unroll
    for (int mf = 0; mf < 4; ++mf){
      const int row = wm * 64 + mf * 16 + lr;
      #pragma unroll
      for (int ks = 0; ks < 2; ++ks)
        a[mf][ks] = *reinterpret_cast<const bf16x8*>(&sA1[row * 64 + ((ks * 4 + lg) ^ (row & 7)) * 8]);
    }
    #pragma unroll
    for (int nf = 0; nf < 4; ++nf){
      const int row = wn * 64 + nf * 16 + lr;
      #pragma unroll
      for (int ks = 0; ks < 2; ++ks)
        b[nf][ks] = *reinterpret_cast<const bf16x8*>(&sB1[row * 64 + ((ks * 4 + lg) ^ (row & 7)) * 8]);
    }
    #pragma unroll
    for (int mf = 0; mf < 4; ++mf)
      #pragma unroll
      for (int nf = 0; nf < 4; ++nf){
        acc1[mf][nf] = MFMA_BF16(a[mf][0], b[nf][0], acc1[mf][nf], 0, 0, 0);
        acc1[mf][nf] = MFMA_BF16(a[mf][1], b[nf][1], acc1[mf][nf], 0, 0, 0);
      }
    __syncthreads();
  }

  // epilogue: y = (inv*acc0 + b0) * silu(acc1 + b1)
  #pragma unroll
  for (int mf = 0; mf < 4; ++mf){
    const int rowb = bm * 128 + wm * 64 + mf * 16 + lg * 4;
    float iv[4];
    #pragma unroll
    for (int r = 0; r < 4; ++r)
      iv[r] = rsqrtf(ssq[rowb + r] * (1.0f / (float)SD) + 1e-6f);
    #pragma unroll
    for (int nf = 0; nf < 4; ++nf){
      const int col = bn * 128 + wn * 64 + nf * 16 + lr;
      const float bb0 = bias0[col], bb1 = bias1[col];
      f32x4 v0 = acc0[mf][nf], v1 = acc1[mf][nf];
      #pragma unroll
      for (int r = 0; r < 4; ++r){
        float p1 = v1[r] + bb1;
        float sg = p1 / (1.f + __expf(-p1));
        out[(size_t)(rowb + r) * GN + col] = (iv[r] * v0[r] + bb0) * sg;
      }
    }
  }
}

// ---------------- chunked complex scan: h[l] = r*h[l-1] + z[l], h[-1] = last_conv ----------------
__global__ __launch_bounds__(256) void k_scan1(const u16* __restrict__ z, float2* __restrict__ carry){
  const int d = blockIdx.x * 256 + threadIdx.x;
  const int c = blockIdx.y, b = blockIdx.z;
  const float sc = exp2f(LOG2_SCALE * ((float)d * (1.0f / 1023.0f)));
  float si, co; sincosf(sc, &si, &co);
  const float er = expf(EPS_PHAZOR);
  const float rre = er * co, rim = er * si;
  const u16* zp = z + ((size_t)b * SL + (size_t)c * CH) * SD + d;
  float hre = 0.f, him = 0.f;
  #pragma unroll 8
  for (int i = 0; i < CH; i++){
    float zv = bf2f(zp[i * SD]);
    float nr = fmaf(rre, hre, fmaf(-rim, him, zv));
    him = fmaf(rre, him, rim * hre);
    hre = nr;
  }
  carry[(size_t)(b * NCHUNK + c) * SD + d] = make_float2(hre, him);
}

__global__ __launch_bounds__(256) void k_scan2(const float2* __restrict__ carry,
    const float* __restrict__ lcre, const float* __restrict__ lcim, float2* __restrict__ hin){
  const int idx = blockIdx.x * 256 + threadIdx.x;  // b*1024 + d
  const int b = idx >> 10, d = idx & 1023;
  const float sc = exp2f(LOG2_SCALE * ((float)d * (1.0f / 1023.0f)));
  float si, co; sincosf((float)CH * sc, &si, &co);
  const float eC = expf((float)CH * EPS_PHAZOR);
  const float Rre = eC * co, Rim = eC * si;
  // prefetch all carries (breaks the dependent-load chain)
  float2 cv[NCHUNK];
  const float2* cp = carry + (size_t)b * NCHUNK * SD + d;
  #pragma unroll
  for (int c = 0; c < NCHUNK; c++) cv[c] = cp[(size_t)c * SD];
  float hre = lcre[d], him = lcim[d];
  float2* hp = hin + (size_t)b * NCHUNK * SD + d;
  #pragma unroll
  for (int c = 0; c < NCHUNK; c++){
    hp[(size_t)c * SD] = make_float2(hre, him);
    float nr = fmaf(Rre, hre, fmaf(-Rim, him, cv[c].x));
    him = fmaf(Rre, him, fmaf(Rim, hre, cv[c].y));
    hre = nr;
  }
}

// scan3: finish the scan in-place AND accumulate per-row sum-of-squares of h (f32, pre-rounding)
__global__ __launch_bounds__(256) void k_scan3(u16* __restrict__ zh, const float2* __restrict__ hin,
                                               float* __restrict__ ssq){
  const int d = blockIdx.x * 256 + threadIdx.x;
  const int c = blockIdx.y, b = blockIdx.z;
  const int ln = threadIdx.x & 63;
  const float sc = exp2f(LOG2_SCALE * ((float)d * (1.0f / 1023.0f)));
  float si, co; sincosf(sc, &si, &co);
  const float er = expf(EPS_PHAZOR);
  const float rre = er * co, rim = er * si;
  float2 h0 = hin[(size_t)(b * NCHUNK + c) * SD + d];
  float hre = h0.x, him = h0.y;
  u16* zp = zh + ((size_t)b * SL + (size_t)c * CH) * SD + d;
  const int rowb = b * SL + c * CH;
  #pragma unroll 4
  for (int i = 0; i < CH; i++){
    float zv = bf2f(zp[i * SD]);
    float nr = fmaf(rre, hre, fmaf(-rim, him, zv));
    him = fmaf(rre, him, rim * hre);
    hre = nr;
    zp[i * SD] = f2bf(hre);   // in-place: z -> Re(h) (bf16)
    // wave-reduce h^2 across the 64 d's this wave covers; one atomic per wave per row
    float p = hre * hre;
    #pragma unroll
    for (int o = 32; o; o >>= 1) p += __shfl_xor(p, o, 64);
    if (ln == 0) atomicAdd(&ssq[rowb + i], p);
  }
}

// ---------------- launch ----------------
extern "C" void kernel_launch(void* const* d_in, const int* in_sizes, int n_in,
                              void* d_out, int out_size, void* d_ws, size_t ws_size,
                              hipStream_t stream){
  const float* x    = (const float*)d_in[0];
  const float* Wz   = (const float*)d_in[1];
  const float* bz   = (const float*)d_in[2];
  const float* Wza  = (const float*)d_in[3];
  const float* bza  = (const float*)d_in[4];
  const float* Wy   = (const float*)d_in[5];
  const float* by   = (const float*)d_in[6];
  const float* Wya  = (const float*)d_in[7];
  const float* bya  = (const float*)d_in[8];
  const float* nw   = (const float*)d_in[9];
  const float* lcre = (const float*)d_in[10];
  const float* lcim = (const float*)d_in[11];

  char* ws = (char*)d_ws;
  // workspace (~76.1 MiB):
  //  [0,32M)   xb (bf16 x)          — live through k_gfinal
  //  [32M,40M) wb: Wz,Wza,Wy',Wya   — Wy' pre-scaled by norm_w
  //  [40M,72M) zb (bf16 z -> Re(h) in place)
  //  [72M,74M) carry ; [74M,76M) hin
  //  [76M,+64K) ssq (f32 per row)
  u16*    xb    = (u16*)(ws);
  u16*    wb    = (u16*)(ws + (32ull << 20));
  u16*    zb    = (u16*)(ws + (40ull << 20));
  float2* carry = (float2*)(ws + (72ull << 20));
  float2* hin   = (float2*)(ws + (74ull << 20));
  float*  ssq   = (float*)(ws + (76ull << 20));
  float*  y     = (float*)d_out;

  const size_t WSZ = (size_t)GK * GN;  // 1M elements per weight

  hipMemsetAsync(ssq, 0, GM * sizeof(float), stream);
  k_convert<<<10240, 256, 0, stream>>>((const float4*)x, (const float4*)Wz, (const float4*)Wza,
                                       (const float4*)Wy, (const float4*)Wya, (const float4*)nw,
                                       xb, wb);
  // z = (x@Wz^T + bz) * silu(x@Wza^T + bza)   [bf16]
  k_gdual<<<1024, 256, 0, stream>>>(xb, wb + 0 * WSZ, wb + 1 * WSZ, bz, bza, zb);
  k_scan1<<<dim3(SD / 256, NCHUNK, SB), 256, 0, stream>>>(zb, carry);
  k_scan2<<<(SB * SD) / 256, 256, 0, stream>>>(carry, lcre, lcim, hin);
  k_scan3<<<dim3(SD / 256, NCHUNK, SB), 256, 0, stream>>>(zb, hin, ssq);
  // y = (rsqrt(mean h^2)+eps) * (h@Wy'^T) + by) * silu(x@Wya^T + bya)
  k_gfinal<<<1024, 256, 0, stream>>>(zb, xb, wb + 2 * WSZ, wb + 3 * WSZ, by, bya, ssq, y);
}